// Round 1
// baseline (575.989 us; speedup 1.0000x reference)
//
#include <hip/hip_runtime.h>
#include <hip/hip_bf16.h>

// Problem: B=16,S=64 -> BS=1024 sequences, L=128 tokens, D=512, F=256 filters
// per conv width Kw in {3,4,5}, V=30000.
// out[bs, c*256 + f] = relu(max_t (conv_c(x)[t,f]) + b_c[f]), fp32.
//
// R2: XOR-swizzle LDS -> conflicts 1.5e8 -> 0 (550->461 us).
// R3: XCD grid remap -> FETCH 1.65->0.70 GB, dur 446: structure-bound.
// R4: slab-resident barrier-free FAILED (877 us): strided B scatter.
// R5: fragment-ordered wq, barrier-free K loop, depth-4 B prefetch: 514 us
//     (conv_gemm 405, MfmaUtil 47%, 2 waves/SIMD, conflicts 2.5e7).
// R6: (a) fuse pack_x into conv_gemm: gather+cvt embed rows straight into
//     LDS (kills the 138 MB x round-trip and its kernel launch);
//     (b) d-split the slab into two 256-wide phases -> LDS 138->67.6 KB;
//     (c) 1024 threads = 16 waves (4m x 4n, 32x64 wave tile, acc 2x4) so
//     regs fit <=128 -> 4 waves/SIMD (TLP vs the 47% MfmaUtil cap);
//     (d) register staging allows the T2 XOR swizzle byte^=((row&7)<<4) on
//     unpadded 512B rows -> conflict-free ds_read_b128, folded into
//     per-parity base regs (zero inner-loop VALU).
//     wq layout unchanged: kq = tap*16 + h*8 + q factors cleanly.

typedef __bf16 bf16x8 __attribute__((ext_vector_type(8)));
typedef float f32x4 __attribute__((ext_vector_type(4)));

#define ROWS 132                       // 128 real + 4 zero rows (K=5 window)
#define ROWB 512                       // 256 bf16 per row-half, no pad (swizzled)
#define SLAB_BYTES (ROWS * ROWB)       // 67584 B
#define WQ_ELEMS 1572864               // 3072 chunks * 512 elem

// -------- pack_w: MFMA-fragment-ordered chunks (unchanged from R5) ----------
// Chunk g = (c, kq, n16), 1024 B = 64 lanes x 16 B. Element (lane, j):
//   f = n16*16 + (lane&15), k = kq*32 + (lane>>4)*8 + j, tap = k>>9, d = k&511
//   src = w_c[f][d][tap]  (layout [F][D][Kw]).
// Chunk bases (chunks): c0 = 0, c1 = 768, c2 = 1792; total 3072.
__global__ void pack_w_kernel(const float* __restrict__ w3,
                              const float* __restrict__ w4,
                              const float* __restrict__ w5,
                              __bf16* __restrict__ wq) {
    const int t    = blockIdx.x * 256 + threadIdx.x;  // 0..196607
    const int g    = t >> 6;                          // chunk 0..3071
    const int lane = t & 63;
    int rel, Kw; const float* w;
    if (g < 768)       { rel = g;        Kw = 3; w = w3; }
    else if (g < 1792) { rel = g - 768;  Kw = 4; w = w4; }
    else               { rel = g - 1792; Kw = 5; w = w5; }
    const int kq  = rel >> 4;
    const int n16 = rel & 15;
    const int f   = n16 * 16 + (lane & 15);
    const int k0  = kq * 32 + (lane >> 4) * 8;        // frag never straddles tap
    const int tap = k0 >> 9;
    const int d0  = k0 & 511;
    const float* src = w + ((size_t)f * 512 + d0) * Kw + tap;
    bf16x8 o;
#pragma unroll
    for (int j = 0; j < 8; ++j) o[j] = (__bf16)src[j * Kw];
    *(bf16x8*)(wq + (size_t)t * 8) = o;
}

// ---------------- fused gather + conv GEMM + max + bias + relu --------------
// Grid 3072 = (bs, conv) with XCD decode. 1024 thr = 16 waves, 4m x 4n wave
// grid, wave tile 32x64 (2x4 of 16x16x32 bf16). Two d-half phases: stage
// embed[text[bs,t]][h*256..+255] as bf16 into swizzled LDS, then barrier-free
// tapped K loop over kq = tap*16 + h*8 + q. B: fragment-ordered wq chunks,
// depth-2 register prefetch.
__global__ __launch_bounds__(1024, 4) void conv_gemm_kernel(
        const int* __restrict__ text,
        const float* __restrict__ embed,
        const __bf16* __restrict__ wq,
        const float* __restrict__ b3,
        const float* __restrict__ b4,
        const float* __restrict__ b5,
        float* __restrict__ out) {
    extern __shared__ char slab[];     // ROWS x 512 B, XOR-swizzled rows

    const int tid  = threadIdx.x;
    const int wave = tid >> 6;         // 0..15
    const int lane = tid & 63;

    const int lin = blockIdx.x;
    const int xcd = lin & 7;
    const int idx = lin >> 3;          // 0..383
    const int bsh = idx / 3;
    const int c   = idx - bsh * 3;     // conv 0..2 (Kw = 3+c)
    const int bs  = bsh * 8 + xcd;     // 0..1023
    const int KW  = 3 + c;
    const size_t cbase = (c == 0) ? 0 : (c == 1) ? 393216 : 917504;  // elems

    // ---- wave grid 4(m) x 4(n); wave tile 32x64 ----
    const int wm = wave & 3, wn = wave >> 2;
    const int lm = lane & 15, lk = lane >> 4;
    const int ls = lane & 31, lh = lane >> 5;     // staging lane split

    const __bf16* bp = wq + cbase + (size_t)(wn * 4) * 512 + lane * 8;

    f32x4 acc[2][4];
#pragma unroll
    for (int i = 0; i < 2; ++i)
#pragma unroll
        for (int j = 0; j < 4; ++j) acc[i][j] = (f32x4){0.f, 0.f, 0.f, 0.f};

    bf16x8 B4[2][4];
    auto loadB = [&](bf16x8* d, int kb) {
        const __bf16* p = bp + (size_t)kb * 8192;
        d[0] = *(const bf16x8*)(p);
        d[1] = *(const bf16x8*)(p + 512);
        d[2] = *(const bf16x8*)(p + 1024);
        d[3] = *(const bf16x8*)(p + 1536);
    };
    auto mfma8 = [&](const bf16x8 a0, const bf16x8 a1, const bf16x8* b) {
#pragma unroll
        for (int nt = 0; nt < 4; ++nt)
            acc[0][nt] = __builtin_amdgcn_mfma_f32_16x16x32_bf16(
                a0, b[nt], acc[0][nt], 0, 0, 0);
#pragma unroll
        for (int nt = 0; nt < 4; ++nt)
            acc[1][nt] = __builtin_amdgcn_mfma_f32_16x16x32_bf16(
                a1, b[nt], acc[1][nt], 0, 0, 0);
    };

    for (int h = 0; h < 2; ++h) {
        const int kq0   = h * 8;
        const int maxkq = (KW - 1) * 16 + h * 8 + 7;

        // B prolog for this phase: in flight during staging (no slab dep).
        loadB(B4[0], kq0);
        loadB(B4[1], kq0 + 1);

        if (h) __syncthreads();        // all slab reads of phase 0 done

        // ---- stage phase h: rows 0..131, 2 rows per wave-iter ----
#pragma unroll
        for (int i = 0; i < 5; ++i) {
            const int r = i * 32 + wave * 2 + lh;
            if (r < ROWS) {
                bf16x8 o = {};
                if (r < 128) {
                    const int tok = text[bs * 128 + r];
                    const float* src = embed + (size_t)tok * 512 + h * 256 + ls * 8;
                    const float4 v0 = *(const float4*)(src);
                    const float4 v1 = *(const float4*)(src + 4);
                    o[0] = (__bf16)v0.x; o[1] = (__bf16)v0.y;
                    o[2] = (__bf16)v0.z; o[3] = (__bf16)v0.w;
                    o[4] = (__bf16)v1.x; o[5] = (__bf16)v1.y;
                    o[6] = (__bf16)v1.z; o[7] = (__bf16)v1.w;
                }
                *(bf16x8*)(slab + r * ROWB + ((ls * 16) ^ ((r & 7) << 4))) = o;
            }
        }
        __syncthreads();

        // ---- barrier-free K loop over this d-half ----
        for (int tap = 0; tap < KW; ++tap) {
            // Per-mt swizzle-folded A bases: addr(q) = P[mt][q&1] + (q>>1)*128
            // where addr = row*512 + ((q*64 + lk*16) ^ ((row&7)<<4)).
            int P[2][2];
#pragma unroll
            for (int mt = 0; mt < 2; ++mt) {
                const int row = wm * 32 + mt * 16 + lm + tap;
                const int x46 = (row & 7) << 4;
                const int Bb  = row * ROWB + ((lk * 16) ^ (x46 & 48));
                const int E   = x46 & 64;
                P[mt][0] = Bb + E;
                P[mt][1] = Bb + 64 - E;
            }
            const int kqt = tap * 16 + h * 8;
#pragma unroll
            for (int q = 0; q < 8; ++q) {
                const bf16x8 a0 = *(const bf16x8*)(slab + P[0][q & 1] + (q >> 1) * 128);
                const bf16x8 a1 = *(const bf16x8*)(slab + P[1][q & 1] + (q >> 1) * 128);
                mfma8(a0, a1, B4[q & 1]);
                // B prefetch for step q+2 (crosses tap at q=6,7; clamp = dead)
                int kqn = kqt + ((q < 6) ? (q + 2) : (q + 10));
                kqn = (kqn <= maxkq) ? kqn : maxkq;
                loadB(B4[q & 1], kqn);
            }
        }
    }

    // ---- epilogue: max over valid t, cross-lane, cross-wave, bias+relu ----
    const int Tv = 126 - c;            // 126/125/124 valid positions
    float cmax[4];
#pragma unroll
    for (int nt = 0; nt < 4; ++nt) {
        float mx = -3.0e38f;
#pragma unroll
        for (int mt = 0; mt < 2; ++mt) {
            const int mb = wm * 32 + mt * 16 + lk * 4;
#pragma unroll
            for (int r = 0; r < 4; ++r) {
                const float v = acc[mt][nt][r];
                if (mb + r < Tv) mx = fmaxf(mx, v);
            }
        }
        mx = fmaxf(mx, __shfl_xor(mx, 16, 64));
        mx = fmaxf(mx, __shfl_xor(mx, 32, 64));
        cmax[nt] = mx;
    }
    __syncthreads();                   // all slab reads done; reuse as red
    float* red = (float*)slab;         // [4][256]
    if (lk == 0) {
#pragma unroll
        for (int nt = 0; nt < 4; ++nt)
            red[wm * 256 + wn * 64 + nt * 16 + lm] = cmax[nt];
    }
    __syncthreads();
    if (tid < 256) {
        const float* bias = (c == 0) ? b3 : (c == 1) ? b4 : b5;
        float v = fmaxf(fmaxf(red[tid], red[256 + tid]),
                        fmaxf(red[512 + tid], red[768 + tid])) + bias[tid];
        out[(size_t)bs * 768 + c * 256 + tid] = fmaxf(v, 0.f);
    }
}

extern "C" void kernel_launch(void* const* d_in, const int* in_sizes, int n_in,
                              void* d_out, int out_size, void* d_ws, size_t ws_size,
                              hipStream_t stream) {
    const int*   text  = (const int*)d_in[0];
    const float* embed = (const float*)d_in[1];
    const float* w3    = (const float*)d_in[2];
    const float* b3    = (const float*)d_in[3];
    const float* w4    = (const float*)d_in[4];
    const float* b4    = (const float*)d_in[5];
    const float* w5    = (const float*)d_in[6];
    const float* b5    = (const float*)d_in[7];
    float* out = (float*)d_out;

    __bf16* wq = (__bf16*)d_ws;                 // 1572864 bf16 = 3.1 MB

    (void)hipFuncSetAttribute((const void*)conv_gemm_kernel,
                              hipFuncAttributeMaxDynamicSharedMemorySize,
                              SLAB_BYTES);

    pack_w_kernel<<<768, 256, 0, stream>>>(w3, w4, w5, wq);
    conv_gemm_kernel<<<3072, 1024, SLAB_BYTES, stream>>>(text, embed, wq,
                                                         b3, b4, b5, out);
}

// Round 2
// 441.657 us; speedup vs baseline: 1.3042x; 1.3042x over previous
//
#include <hip/hip_runtime.h>
#include <hip/hip_bf16.h>

// Problem: B=16,S=64 -> BS=1024 sequences, L=128 tokens, D=512, F=256 filters
// per conv width Kw in {3,4,5}, V=30000.
// out[bs, c*256 + f] = relu(max_t (conv_c(x)[t,f]) + b_c[f]), fp32.
//
// R5: fragment-ordered wq, barrier-free K loop: 514 us (conv 405, Mfma 47%).
// R6: fused gather + 16 waves FAILED (562): 6 gathers/bs -> 786 MB L2 storm,
//     B prefetch halved (depth2, 256->512 B/MFMA) -> MFMA starved (33.5%).
//     Bank conflicts invariant 4 cyc/ds_read_b128 across pad vs swizzle.
// R7: persistent c-merged blocks: grid 256, 4 bs/block, both half-D slabs
//     (67.6 KB x2) resident across all 3 convs -> 2 gathers/bs (262 MB).
//     Next-bs gather issued early / ds-written after phase barrier (hidden).
//     16 waves as 2m x 8n (tile 64x32, acc 4x2): 8 MFMA per 2 KB B chunk
//     (256 B/MFMA) + depth-4 B ring (~620 cyc cover). setprio around MFMA.

typedef __bf16 bf16x8 __attribute__((ext_vector_type(8)));
typedef float f32x4 __attribute__((ext_vector_type(4)));

#define ROWS 132                      // 128 real + 4 zero rows (K=5 window)
#define ROWB 512                      // bytes per row per half-D buffer
#define BUF_BYTES (ROWS * ROWB)       // 67584
#define RED_OFF (2 * BUF_BYTES)
#define LDS_TOTAL (2 * BUF_BYTES + 2048)   // 139264... (2 KB red) = 137216+2048? see launch
#define WQ_ELEMS 1572864              // 3072 chunks * 512 elem

// -------- pack_w: MFMA-fragment-ordered chunks (unchanged) ------------------
// Chunk g = (c, kq, n16), 1024 B = 64 lanes x 16 B. Element (lane, j):
//   f = n16*16 + (lane&15), k = kq*32 + (lane>>4)*8 + j, tap = k>>9, d = k&511
//   src = w_c[f][d][tap]  (layout [F][D][Kw]).
__global__ void pack_w_kernel(const float* __restrict__ w3,
                              const float* __restrict__ w4,
                              const float* __restrict__ w5,
                              __bf16* __restrict__ wq) {
    const int t    = blockIdx.x * 256 + threadIdx.x;  // 0..196607
    const int g    = t >> 6;                          // chunk 0..3071
    const int lane = t & 63;
    int rel, Kw; const float* w;
    if (g < 768)       { rel = g;        Kw = 3; w = w3; }
    else if (g < 1792) { rel = g - 768;  Kw = 4; w = w4; }
    else               { rel = g - 1792; Kw = 5; w = w5; }
    const int kq  = rel >> 4;
    const int n16 = rel & 15;
    const int f   = n16 * 16 + (lane & 15);
    const int k0  = kq * 32 + (lane >> 4) * 8;
    const int tap = k0 >> 9;
    const int d0  = k0 & 511;
    const float* src = w + ((size_t)f * 512 + d0) * Kw + tap;
    bf16x8 o;
#pragma unroll
    for (int j = 0; j < 8; ++j) o[j] = (__bf16)src[j * Kw];
    *(bf16x8*)(wq + (size_t)t * 8) = o;
}

// ---------------- persistent fused gather + conv GEMM -----------------------
__global__ __launch_bounds__(1024, 4) void conv_gemm_kernel(
        const int* __restrict__ text,
        const float* __restrict__ embed,
        const __bf16* __restrict__ wq,
        const float* __restrict__ b3,
        const float* __restrict__ b4,
        const float* __restrict__ b5,
        float* __restrict__ out) {
    extern __shared__ char lds[];
    char* const buf0 = lds;
    char* const buf1 = lds + BUF_BYTES;
    float* const red = (float*)(lds + RED_OFF);

    const int tid  = threadIdx.x;
    const int lane = tid & 63;
    const int wave = tid >> 6;         // 0..15
    const int wm = wave & 1;           // m-half 0..1 (64 rows each)
    const int wn = wave >> 1;          // n-slice 0..7 (32 cols each)
    const int lm = lane & 15, lk = lane >> 4;
    const int sr = tid >> 5;           // staging row-in-pass 0..31
    const int sc = tid & 31;           // staging col 0..31 (x16B)

    // ---- gather staging: 2 passes (64 rows) per pair, 16 B dst/thread ----
    float4 G[4];
    auto issuePair = [&](int nbs, int h, int p0) {
#pragma unroll
        for (int p = 0; p < 2; ++p) {
            const int r = (p0 + p) * 32 + sr;
            const int tok = text[nbs * 128 + r];
            const float* src = embed + (size_t)tok * 512 + h * 256 + sc * 8;
            G[p * 2]     = *(const float4*)(src);
            G[p * 2 + 1] = *(const float4*)(src + 4);
        }
    };
    auto writePair = [&](char* bufp, int p0) {
#pragma unroll
        for (int p = 0; p < 2; ++p) {
            const int r = (p0 + p) * 32 + sr;
            const float4 v0 = G[p * 2], v1 = G[p * 2 + 1];
            bf16x8 o;
            o[0] = (__bf16)v0.x; o[1] = (__bf16)v0.y;
            o[2] = (__bf16)v0.z; o[3] = (__bf16)v0.w;
            o[4] = (__bf16)v1.x; o[5] = (__bf16)v1.y;
            o[6] = (__bf16)v1.z; o[7] = (__bf16)v1.w;
            *(bf16x8*)(bufp + r * ROWB + ((sc * 16) ^ ((r & 7) << 4))) = o;
        }
    };

    f32x4 acc[4][2];
    bf16x8 B4[4][2];
    const __bf16* bp = wq;             // set per conv

    auto loadB = [&](bf16x8* d, int kb) {
        const __bf16* p = bp + (size_t)kb * 8192;
        d[0] = *(const bf16x8*)(p);
        d[1] = *(const bf16x8*)(p + 512);
    };

    // One d-half phase: KW taps x 8 unrolled kq-steps, barrier-free.
    auto runPhase = [&](const char* bufp, int KW, int h) {
        const int kh = h * 8;
        const int maxkq = (KW - 1) * 16 + kh + 7;
        loadB(B4[0], kh);     loadB(B4[1], kh + 1);
        loadB(B4[2], kh + 2); loadB(B4[3], kh + 3);
        for (int tap = 0; tap < KW; ++tap) {
            // swizzle-folded A bases: addr(q) = P[mt][q&1] + (q>>1)*128
            int P[4][2];
#pragma unroll
            for (int mt = 0; mt < 4; ++mt) {
                const int row = wm * 64 + mt * 16 + lm + tap;
                const int x46 = (row & 7) << 4;
                const int Bb  = row * ROWB + ((lk * 16) ^ (x46 & 48));
                const int E   = x46 & 64;
                P[mt][0] = Bb + E;
                P[mt][1] = Bb + 64 - E;
            }
            const int kqt = tap * 16 + kh;
#pragma unroll
            for (int q = 0; q < 8; ++q) {
                bf16x8 a[4];
#pragma unroll
                for (int mt = 0; mt < 4; ++mt)
                    a[mt] = *(const bf16x8*)(bufp + P[mt][q & 1] + (q >> 1) * 128);
                __builtin_amdgcn_s_setprio(1);
#pragma unroll
                for (int nt = 0; nt < 2; ++nt)
#pragma unroll
                    for (int mt = 0; mt < 4; ++mt)
                        acc[mt][nt] = __builtin_amdgcn_mfma_f32_16x16x32_bf16(
                            a[mt], B4[q & 3][nt], acc[mt][nt], 0, 0, 0);
                __builtin_amdgcn_s_setprio(0);
                // B prefetch for step s+4 (ring slot q&3); clamp = dead dup
                int kqn = kqt + ((q < 4) ? (q + 4) : (q + 12));
                kqn = (kqn <= maxkq) ? kqn : maxkq;
                loadB(B4[q & 3], kqn);
            }
        }
    };

    // ---- prolog: stage bs(i=0) both halves + zero pad rows (once) ----
    const int bsbase = blockIdx.x * 4;
    issuePair(bsbase, 0, 0); writePair(buf0, 0);
    issuePair(bsbase, 0, 2); writePair(buf0, 2);
    issuePair(bsbase, 1, 0); writePair(buf1, 0);
    issuePair(bsbase, 1, 2); writePair(buf1, 2);
    if (tid < 128) {                   // rows 128..131, both buffers, once
        const int r = 128 + sr;
        const int off = r * ROWB + ((sc * 16) ^ ((r & 7) << 4));
        bf16x8 z = {};
        *(bf16x8*)(buf0 + off) = z;
        *(bf16x8*)(buf1 + off) = z;
    }
    __syncthreads();

#pragma unroll 1
    for (int i = 0; i < 4; ++i) {
        const int bs  = bsbase + i;
        const int nbs = bs + 1;
        const bool stg = (i < 3);
#pragma unroll 1
        for (int c = 0; c < 3; ++c) {
            const int KW = 3 + c;
            bp = wq + ((c == 0) ? 0 : (c == 1) ? 393216 : 917504)
                    + (size_t)wn * 1024 + (size_t)lane * 8;
#pragma unroll
            for (int mt = 0; mt < 4; ++mt)
#pragma unroll
                for (int nt = 0; nt < 2; ++nt)
                    acc[mt][nt] = (f32x4){0.f, 0.f, 0.f, 0.f};

            const bool lastc = stg && (c == 2);
            if (lastc) issuePair(nbs, 0, 0);   // h0 rows 0..63: hide under phase
            runPhase(buf0, KW, 0);
            if (lastc) {
                __syncthreads();               // all buf0 reads done
                writePair(buf0, 0);
                issuePair(nbs, 0, 2);          // h0 rows 64..127 (short stall)
                writePair(buf0, 2);
                issuePair(nbs, 1, 0);          // h1 rows 0..63: hide under phase
            }
            runPhase(buf1, KW, 1);

            // ---- epilogue conv c: masked max, cross-lane, cross-wave ----
            const int Tv = 126 - c;            // 126/125/124 valid positions
            float cmax[2];
#pragma unroll
            for (int nt = 0; nt < 2; ++nt) {
                float mx = -3.0e38f;
#pragma unroll
                for (int mt = 0; mt < 4; ++mt) {
                    const int mb = wm * 64 + mt * 16 + lk * 4;
#pragma unroll
                    for (int r = 0; r < 4; ++r)
                        if (mb + r < Tv) mx = fmaxf(mx, acc[mt][nt][r]);
                }
                mx = fmaxf(mx, __shfl_xor(mx, 16, 64));
                mx = fmaxf(mx, __shfl_xor(mx, 32, 64));
                cmax[nt] = mx;
            }
            __syncthreads();                   // buf1 reads + prev red reads done
            if (lastc) {
                writePair(buf1, 0);
                issuePair(nbs, 1, 2);          // h1 rows 64..127 (short stall)
                writePair(buf1, 2);
            }
            if (lk == 0) {
#pragma unroll
                for (int nt = 0; nt < 2; ++nt)
                    red[wm * 256 + wn * 32 + nt * 16 + lm] = cmax[nt];
            }
            __syncthreads();
            if (tid < 256) {
                const float* bias = (c == 0) ? b3 : (c == 1) ? b4 : b5;
                const float v = fmaxf(red[tid], red[256 + tid]) + bias[tid];
                out[(size_t)bs * 768 + c * 256 + tid] = fmaxf(v, 0.f);
            }
        }
    }
}

extern "C" void kernel_launch(void* const* d_in, const int* in_sizes, int n_in,
                              void* d_out, int out_size, void* d_ws, size_t ws_size,
                              hipStream_t stream) {
    const int*   text  = (const int*)d_in[0];
    const float* embed = (const float*)d_in[1];
    const float* w3    = (const float*)d_in[2];
    const float* b3    = (const float*)d_in[3];
    const float* w4    = (const float*)d_in[4];
    const float* b4    = (const float*)d_in[5];
    const float* w5    = (const float*)d_in[6];
    const float* b5    = (const float*)d_in[7];
    float* out = (float*)d_out;

    __bf16* wq = (__bf16*)d_ws;                 // 1572864 bf16 = 3.1 MB

    (void)hipFuncSetAttribute((const void*)conv_gemm_kernel,
                              hipFuncAttributeMaxDynamicSharedMemorySize,
                              LDS_TOTAL);

    pack_w_kernel<<<768, 256, 0, stream>>>(w3, w4, w5, wq);
    conv_gemm_kernel<<<256, 1024, LDS_TOTAL, stream>>>(text, embed, wq,
                                                       b3, b4, b5, out);
}